// Round 2
// baseline (190.279 us; speedup 1.0000x reference)
//
#include <hip/hip_runtime.h>

// BatchBlur via bf16 MFMA banded-Toeplitz. R6 = R5 with the ky loop software-
// pipelined one iteration deep: while MFMAing ky's fragments (loads completed
// last iteration -> no lgkmcnt wait), issue ky's high-group B-reads, ky+1's
// low-group B-reads and ky+1's A-window reads (13 LDS ops in flight behind
// every MFMA phase). Manual 2x unroll with swapped register sets (static
// indexing, zero v_movs). Note: SQ_LDS_BANK_CONFLICT ~1920/block is intrinsic
// b128 cost (12cyc vs 8 ideal), not a layout bug -- do not chase with swizzles.
// Layouts unchanged (verified): A: m=lane&15,k=q*8+j ; B: n=lane&15,k=q*8+j ;
// D: n=lane&15, m=q*4+reg.

#define HH 512
#define WW 512
#define LL 15
#define PP 7
#define TW 128
#define TH 64
#define SH (TH + LL - 1)          // 78
#define SWB 152                   // slab row in bf16 elems; 304B rows, 16B-aligned
#define KPAD 64                   // kernel row pad (128B)
#define NSEG 8
#define NROWIT 13                 // 78 rows / 6 row-starts

typedef __attribute__((ext_vector_type(8))) short bf16x8;
typedef __attribute__((ext_vector_type(4))) float f32x4;

__device__ inline unsigned short f2bf(float f) {
    unsigned u = __builtin_bit_cast(unsigned, f);
    return (unsigned short)((u + 0x7fffu + ((u >> 16) & 1u)) >> 16);   // RNE
}

__device__ inline unsigned cvt_pk_bf16(float lo, float hi) {
    unsigned r;
    asm("v_cvt_pk_bf16_f32 %0, %1, %2" : "=v"(r) : "v"(lo), "v"(hi));
    return r;
}

// Banded A fragment: elements e..e+7 of zero-padded kernel row ky, via five
// 4B-aligned LDS dwords + 32-bit funnel shifts (sh in {0,16}).
__device__ __forceinline__ bf16x8 abuild(const unsigned short* sk, int ky,
                                         int base, int sh) {
    const int* rp = (const int*)&sk[ky * KPAD];
    int v0 = rp[base], v1 = rp[base + 1], v2 = rp[base + 2],
        v3 = rp[base + 3], v4 = rp[base + 4];
    int r0 = (int)(unsigned)((((unsigned long long)(unsigned)v1 << 32) | (unsigned)v0) >> sh);
    int r1 = (int)(unsigned)((((unsigned long long)(unsigned)v2 << 32) | (unsigned)v1) >> sh);
    int r2 = (int)(unsigned)((((unsigned long long)(unsigned)v3 << 32) | (unsigned)v2) >> sh);
    int r3 = (int)(unsigned)((((unsigned long long)(unsigned)v4 << 32) | (unsigned)v3) >> sh);
    return __builtin_bit_cast(bf16x8, (int4){r0, r1, r2, r3});
}

// One ky step: issue high-group reads + next-ky prefetch, then MFMA current.
__device__ __forceinline__ void half_step(
    const unsigned short* sx, const unsigned short* sk,
    int rowbase, int q, int ky, int base, int sh, bool pf,
    bf16x8& acur, bf16x8 (&blcur)[4], bf16x8& anxt, bf16x8 (&blnxt)[4],
    bf16x8 (&bh)[4], f32x4 (&acc)[8])
{
    const unsigned short* srow = &sx[(rowbase + ky) * SWB + q * 8];
    #pragma unroll
    for (int s = 0; s < 4; ++s) bh[s] = *(const bf16x8*)&srow[(s + 4) * 16];
    if (pf) {
        const unsigned short* srown = srow + SWB;
        #pragma unroll
        for (int s = 0; s < 4; ++s) blnxt[s] = *(const bf16x8*)&srown[s * 16];
        anxt = abuild(sk, ky + 1, base, sh);
    }
    #pragma unroll
    for (int s = 0; s < 4; ++s)
        acc[s] = __builtin_amdgcn_mfma_f32_16x16x32_bf16(acur, blcur[s], acc[s], 0, 0, 0);
    #pragma unroll
    for (int s = 0; s < 4; ++s)
        acc[s + 4] = __builtin_amdgcn_mfma_f32_16x16x32_bf16(acur, bh[s], acc[s + 4], 0, 0, 0);
}

__global__ __launch_bounds__(256, 6)
void batchblur_mfma(const float* __restrict__ x,
                    const float* __restrict__ kern,
                    float* __restrict__ out)
{
    __shared__ unsigned short sx[SH * SWB];   // 23712 B
    __shared__ unsigned short sk[LL * KPAD];  // 1920 B

    const int tid   = threadIdx.x;
    const int ox0   = blockIdx.x * TW;
    const int oy0   = blockIdx.y * TH;
    const int plane = blockIdx.z;
    const int b     = plane / 3;

    const float* __restrict__ xp = x + (size_t)plane * (HH * WW);
    const float* __restrict__ kp = kern + b * (LL * LL);

    // ---- sx staging, phase 1: issue ALL global loads into registers ----
    // 228 active threads = 38 col-quads x 6 row-starts; 13 row-iters each.
    const bool act = tid < 228;
    int r0 = 0, c4 = 0;
    int gx[4];
    float vv[NROWIT][4];
    if (act) {
        r0 = tid / 38;                 // 0..5
        c4 = (tid - r0 * 38) * 4;      // 0..148
        #pragma unroll
        for (int j = 0; j < 4; ++j) {
            int g = ox0 + c4 + j - PP;
            gx[j] = g < 0 ? -g : (g >= WW ? 2 * WW - 2 - g : g);
        }
        #pragma unroll
        for (int k = 0; k < NROWIT; ++k) {
            int gy = oy0 + (r0 + 6 * k) - PP;
            gy = gy < 0 ? -gy : (gy >= HH ? 2 * HH - 2 - gy : gy);
            const float* __restrict__ rowp = xp + (size_t)gy * WW;
            #pragma unroll
            for (int j = 0; j < 4; ++j) vv[k][j] = rowp[gx[j]];
        }
    }

    // ---- stage zero-padded kernel rows (bf16) while sx loads are in flight ----
    for (int i = tid; i < LL * KPAD; i += 256) {
        int ky = i >> 6, c = i & 63;
        float v = (c >= 16 && c < 16 + LL) ? kp[ky * LL + (c - 16)] : 0.f;
        sk[i] = f2bf(v);
    }

    // ---- sx staging, phase 2: convert (packed RNE) + ds_write_b64 ----
    if (act) {
        #pragma unroll
        for (int k = 0; k < NROWIT; ++k) {
            int r = r0 + 6 * k;
            uint2 pk;
            pk.x = cvt_pk_bf16(vv[k][0], vv[k][1]);
            pk.y = cvt_pk_bf16(vv[k][2], vv[k][3]);
            *(uint2*)&sx[r * SWB + c4] = pk;
        }
    }
    __syncthreads();

    const int lane = tid & 63;
    const int t    = lane & 15;       // A row m / B-D col n
    const int q    = lane >> 4;       // quad
    const int g    = tid >> 6;        // wave -> 16-row group
    const int rowbase = g * 16 + t;

    f32x4 acc[NSEG];
    #pragma unroll
    for (int s = 0; s < NSEG; ++s) acc[s] = (f32x4){0.f, 0.f, 0.f, 0.f};

    // A-build geometry (loop-invariant).
    const int e    = 16 + q * 8 - t;  // in [1, 40]
    const int b0   = 2 * e;           // in [2, 80]
    const int base = (b0 & ~3) >> 2;  // dword index, in [0, 20]; base+4 <= 24 < 32
    const int sh   = (b0 & 3) * 8;    // 0 or 16

    // ---- software-pipelined ky loop: 7 x (2 steps) + tail ----
    bf16x8 a0 = abuild(sk, 0, base, sh), a1;
    bf16x8 bl0[4], bl1[4], bh[4];
    {
        const unsigned short* srow = &sx[rowbase * SWB + q * 8];
        #pragma unroll
        for (int s = 0; s < 4; ++s) bl0[s] = *(const bf16x8*)&srow[s * 16];
    }
    #pragma unroll 1
    for (int kk = 0; kk < 7; ++kk) {
        half_step(sx, sk, rowbase, q, 2 * kk,     base, sh, true, a0, bl0, a1, bl1, bh, acc);
        half_step(sx, sk, rowbase, q, 2 * kk + 1, base, sh, true, a1, bl1, a0, bl0, bh, acc);
    }
    half_step(sx, sk, rowbase, q, 14, base, sh, false, a0, bl0, a1, bl1, bh, acc);

    // ---- store: 8 x float4, D layout n=lane&15 (row), m=q*4+reg (col) ----
    float* __restrict__ op = out + (size_t)plane * (HH * WW) + (size_t)(oy0 + rowbase) * WW + ox0;
    #pragma unroll
    for (int s = 0; s < NSEG; ++s) {
        float* dst = op + s * 16 + q * 4;
        *(float4*)dst = make_float4(acc[s][0], acc[s][1], acc[s][2], acc[s][3]);
    }
}

extern "C" void kernel_launch(void* const* d_in, const int* in_sizes, int n_in,
                              void* d_out, int out_size, void* d_ws, size_t ws_size,
                              hipStream_t stream) {
    const float* x  = (const float*)d_in[0];
    const float* kn = (const float*)d_in[1];
    float* out      = (float*)d_out;
    dim3 grid(WW / TW, HH / TH, 32 * 3);   // (4, 8, 96)
    batchblur_mfma<<<grid, dim3(256), 0, stream>>>(x, kn, out);
}